// Round 1
// baseline (926.660 us; speedup 1.0000x reference)
//
#include <hip/hip_runtime.h>
#include <stdint.h>

#define NIMG 512
#define CINCH 64
#define HIDC 128
#define NEDGE 16384
#define HWPIX 1024
#define PW2 34
#define PPIX 1156   // 34*34

typedef __attribute__((ext_vector_type(8))) short bf16x8;
typedef __attribute__((ext_vector_type(4))) float f32x4;

static __device__ __forceinline__ unsigned short f2bf(float f){
  unsigned u = __builtin_bit_cast(unsigned, f);
  u += 0x7FFFu + ((u>>16)&1u);
  return (unsigned short)(u>>16);
}
static __device__ __forceinline__ float bf2f(unsigned short s){
  unsigned u = ((unsigned)s)<<16;
  return __builtin_bit_cast(float, u);
}

// ---------------- init: zero pad borders + accumulators + csr counters ------
__global__ void k_init(unsigned short* xe_pad, unsigned short* xp1_pad,
                       float* xnode_acc, int* cnt, int* pos){
  int idx = blockIdx.x*256 + threadIdx.x;
  int total_b = NIMG*132*16;
  for(int i = idx; i < total_b; i += gridDim.x*256){
    int img = i / (132*16);
    int rem = i - img*(132*16);
    int bp = rem >> 4;
    int slot = rem & 15;
    int r, c;
    if(bp < 34){ r = 0; c = bp; }
    else if(bp < 68){ r = 33; c = bp-34; }
    else if(bp < 100){ r = bp-68+1; c = 0; }
    else { r = bp-100+1; c = 33; }
    size_t off = ((size_t)img*PPIX + r*PW2 + c)*128 + slot*8;
    uint4 z = {0,0,0,0};
    *(uint4*)(xe_pad + off) = z;
    *(uint4*)(xp1_pad + off) = z;
  }
  for(int i = idx; i < NIMG*HIDC; i += gridDim.x*256) xnode_acc[i] = 0.f;
  for(int i = idx; i < NIMG; i += gridDim.x*256){ cnt[i] = 0; pos[i] = 0; }
}

// ---------------- weight conversion to pre-swizzled bf16 LDS images ---------
// LDS image row (256B or 128B): slot s holds input-channel group (s ^ (co&7))
__global__ void k_wconv(const float* __restrict__ sp_w1, const float* __restrict__ sp_w2,
                        const float* __restrict__ fe_w, const float* __restrict__ op_w,
                        unsigned short* Wb1, unsigned short* Wb2,
                        unsigned short* Wfe, unsigned short* Wop){
  int idx = blockIdx.x*256 + threadIdx.x;
  for(int i = idx; i < 147456; i += gridDim.x*256){
    int j = i & 7, s = (i>>3)&15, co = (i>>7)&127, tap = i>>14;
    int cin = ((s ^ (co&7))<<3) + j;
    Wb1[i] = f2bf(sp_w1[(co*128+cin)*9 + tap]);
    Wb2[i] = f2bf(sp_w2[(co*128+cin)*9 + tap]);
  }
  for(int i = idx; i < 8192; i += gridDim.x*256){
    int j = i & 7, s = (i>>3)&7, co = i>>6;
    int ci = ((s ^ (co&7))<<3) + j;
    Wfe[i] = f2bf(fe_w[co*64+ci]);
  }
  for(int i = idx; i < 8192; i += gridDim.x*256){
    int j = i & 7, s = (i>>3)&15, co = i>>7;   // co 0..63
    int cin = ((s ^ (co&7))<<3) + j;
    Wop[i] = f2bf(op_w[co*128+cin]);
  }
}

// ---------------- CSR build ------------------------------------------------
__global__ void k_csr_count(const int* __restrict__ ei, int* cnt){
  int e = blockIdx.x*256 + threadIdx.x;
  if(e < NEDGE) atomicAdd(&cnt[ei[NEDGE+e]], 1);
}
__global__ void k_csr_scan(const int* __restrict__ cnt, int* offs){
  __shared__ int sc[512];
  int t = threadIdx.x;
  sc[t] = cnt[t] + 1;   // +1 for self loop
  __syncthreads();
  for(int o = 1; o < 512; o <<= 1){
    int add = (t >= o) ? sc[t-o] : 0;
    __syncthreads();
    sc[t] += add;
    __syncthreads();
  }
  if(t == 0) offs[0] = 0;
  offs[t+1] = sc[t];
}
__global__ void k_csr_fill(const int* __restrict__ ei, const int* __restrict__ offs,
                           int* pos, int* csr_src){
  int e = blockIdx.x*256 + threadIdx.x;
  if(e < NEDGE + NIMG){
    int s, d;
    if(e < NEDGE){ s = ei[e]; d = ei[NEDGE+e]; }
    else { s = e - NEDGE; d = s; }
    int slot = offs[d] + atomicAdd(&pos[d], 1);
    csr_src[slot] = s;
  }
}

// ---------------- encode: 1x1 conv + BN + relu + conf, write padded NHWC ----
__launch_bounds__(256, 2)
__global__ void k_encode(const float* __restrict__ x, const float* __restrict__ conf,
                         const unsigned short* __restrict__ Wfe,
                         const float* __restrict__ fe_b, const float* __restrict__ fe_g,
                         const float* __restrict__ fe_beta,
                         unsigned short* __restrict__ xe_pad){
  __shared__ char lds[49152];          // xa 32KB (f32 swizzled) + wb 16KB
  char* xa = lds; char* wb = lds + 32768;
  int tid = threadIdx.x;
  int n = blockIdx.x >> 3, rg = blockIdx.x & 7;
  int hw0 = rg*128;
  {
    int q = tid >> 3, c0 = tid & 7;
    const float* xb = x + (size_t)n*CINCH*HWPIX + hw0;
    #pragma unroll
    for(int cc = 0; cc < 8; ++cc){
      int c = cc*8 + c0;
      float4 v = *(const float4*)(xb + (size_t)c*HWPIX + q*4);
      float vv[4] = {v.x, v.y, v.z, v.w};
      #pragma unroll
      for(int i = 0; i < 4; ++i){
        int p = q*4 + i;
        *(float*)(xa + p*256 + ((cc ^ (p&7))*32) + c0*4) = vv[i];
      }
    }
    #pragma unroll
    for(int it = 0; it < 4; ++it){
      uint4 w = *(const uint4*)((const char*)Wfe + it*4096 + tid*16);
      *(uint4*)(wb + it*4096 + tid*16) = w;
    }
  }
  __syncthreads();
  int wid = tid>>6, lane = tid&63;
  int wr = wid>>1, wc = wid&1, fr = lane&15, fq = lane>>4;
  f32x4 acc[4][4];
  #pragma unroll
  for(int a = 0; a < 4; ++a)
    #pragma unroll
    for(int b = 0; b < 4; ++b) acc[a][b] = (f32x4){0.f,0.f,0.f,0.f};
  #pragma unroll
  for(int kc = 0; kc < 2; ++kc){
    bf16x8 af[4], bfr[4];
    #pragma unroll
    for(int mi = 0; mi < 4; ++mi){
      int p = wr*64 + mi*16 + fr;
      int u = kc*4 + fq;
      const float* src = (const float*)(xa + p*256 + ((u ^ (p&7))*32));
      float4 lo = *(const float4*)src;
      float4 hi = *(const float4*)(src+4);
      bf16x8 a;
      a[0]=(short)f2bf(lo.x); a[1]=(short)f2bf(lo.y); a[2]=(short)f2bf(lo.z); a[3]=(short)f2bf(lo.w);
      a[4]=(short)f2bf(hi.x); a[5]=(short)f2bf(hi.y); a[6]=(short)f2bf(hi.z); a[7]=(short)f2bf(hi.w);
      af[mi] = a;
    }
    #pragma unroll
    for(int nf = 0; nf < 4; ++nf){
      int co = wc*64 + nf*16 + fr;
      int slot = (kc*4 + fq) ^ (co&7);
      bfr[nf] = *(const bf16x8*)(wb + co*128 + slot*16);
    }
    #pragma unroll
    for(int mi = 0; mi < 4; ++mi)
      #pragma unroll
      for(int nf = 0; nf < 4; ++nf)
        acc[mi][nf] = __builtin_amdgcn_mfma_f32_16x16x32_bf16(af[mi], bfr[nf], acc[mi][nf], 0,0,0);
  }
  __syncthreads();
  {
    const float rs = 0.9999950000374997f;
    float kb[4], ks[4], kbe[4];
    #pragma unroll
    for(int nf = 0; nf < 4; ++nf){
      int co = wc*64 + nf*16 + fr;
      kb[nf] = fe_b[co]; ks[nf] = fe_g[co]*rs; kbe[nf] = fe_beta[co];
    }
    #pragma unroll
    for(int mi = 0; mi < 4; ++mi)
      #pragma unroll
      for(int j = 0; j < 4; ++j){
        int px = wr*64 + mi*16 + fq*4 + j;
        float cf = conf[(size_t)n*HWPIX + hw0 + px];
        #pragma unroll
        for(int nf = 0; nf < 4; ++nf){
          float v = (acc[mi][nf][j] + kb[nf])*ks[nf] + kbe[nf];
          v = fmaxf(v, 0.f)*cf;
          int co = wc*64 + nf*16 + fr;
          *(unsigned short*)(xa + px*256 + ((co*2) ^ (((px>>2)&7)<<4))) = f2bf(v);
        }
      }
  }
  __syncthreads();
  {
    int p = tid>>1, half = tid&1;
    int r = rg*4 + (p>>5), c = p&31;
    unsigned short* dst = xe_pad + ((size_t)n*PPIX + (r+1)*PW2 + (c+1))*128 + half*64;
    #pragma unroll
    for(int s = 0; s < 8; ++s){
      int slot = half*8 + s;
      uint4 v = *(uint4*)(xa + p*256 + ((slot*16) ^ (((p>>2)&7)<<4)));
      *(uint4*)(dst + s*8) = v;
    }
  }
}

// ---------------- 3x3 conv as 9 shifted GEMMs, padded input -----------------
__launch_bounds__(256, 2)
__global__ void k_conv3(const unsigned short* __restrict__ inp,   // padded NHWC bf16
                        const unsigned short* __restrict__ Wb,    // [9][128][16slots][8] pre-swizzled
                        const float* __restrict__ bnb, const float* __restrict__ bng,
                        const float* __restrict__ bnbe,
                        unsigned short* __restrict__ outp,
                        float* __restrict__ xnode_acc, int mode){  // 0: padded out, 1: flat out + xnode
  __shared__ char lds[65536];
  int tid = threadIdx.x;
  int n = blockIdx.x>>3, rg = blockIdx.x&7;
  int wid = tid>>6, lane = tid&63;
  int wr = wid>>1, wc = wid&1, fr = lane&15, fq = lane>>4;
  const unsigned short* ibase = inp + (size_t)n*PPIX*128;
  int aoff[4];
  #pragma unroll
  for(int mi = 0; mi < 4; ++mi){
    int p = wr*64 + mi*16 + fr;
    int r = rg*4 + (p>>5), c = p&31;
    aoff[mi] = ((r+1)*PW2 + (c+1))*128 + fq*8;
  }
  f32x4 acc[4][4];
  #pragma unroll
  for(int a = 0; a < 4; ++a)
    #pragma unroll
    for(int b = 0; b < 4; ++b) acc[a][b] = (f32x4){0.f,0.f,0.f,0.f};

  const char* wsrc = (const char*)Wb;
  uint4 st[8];
  #pragma unroll
  for(int it = 0; it < 8; ++it) st[it] = *(const uint4*)(wsrc + it*4096 + tid*16);
  #pragma unroll
  for(int it = 0; it < 8; ++it) *(uint4*)(lds + it*4096 + tid*16) = st[it];
  __syncthreads();

  for(int tap = 0; tap < 9; ++tap){
    char* cur = lds + (tap&1)*32768;
    int dy = tap/3 - 1, dx = tap - (tap/3)*3 - 1;
    int toff = (dy*PW2 + dx)*128;
    if(tap < 8){
      #pragma unroll
      for(int it = 0; it < 8; ++it)
        st[it] = *(const uint4*)(wsrc + (size_t)(tap+1)*32768 + it*4096 + tid*16);
    }
    #pragma unroll
    for(int kc = 0; kc < 4; ++kc){
      bf16x8 af[4], bfr[4];
      #pragma unroll
      for(int mi = 0; mi < 4; ++mi)
        af[mi] = *(const bf16x8*)(ibase + aoff[mi] + toff + kc*32);
      #pragma unroll
      for(int nf = 0; nf < 4; ++nf){
        int co = wc*64 + nf*16 + fr;
        int slot = (kc*4 + fq) ^ (co&7);
        bfr[nf] = *(const bf16x8*)(cur + co*256 + slot*16);
      }
      #pragma unroll
      for(int mi = 0; mi < 4; ++mi)
        #pragma unroll
        for(int nf = 0; nf < 4; ++nf)
          acc[mi][nf] = __builtin_amdgcn_mfma_f32_16x16x32_bf16(af[mi], bfr[nf], acc[mi][nf], 0,0,0);
    }
    if(tap < 8){
      char* nxt = lds + ((tap+1)&1)*32768;
      #pragma unroll
      for(int it = 0; it < 8; ++it) *(uint4*)(nxt + it*4096 + tid*16) = st[it];
    }
    __syncthreads();
  }
  // epilogue: BN + relu -> LDS transpose -> coalesced store
  {
    const float rs = 0.9999950000374997f;
    float kb[4], ks[4], kbe[4];
    #pragma unroll
    for(int nf = 0; nf < 4; ++nf){
      int co = wc*64 + nf*16 + fr;
      kb[nf] = bnb[co]; ks[nf] = bng[co]*rs; kbe[nf] = bnbe[co];
    }
    #pragma unroll
    for(int mi = 0; mi < 4; ++mi)
      #pragma unroll
      for(int j = 0; j < 4; ++j){
        int px = wr*64 + mi*16 + fq*4 + j;
        #pragma unroll
        for(int nf = 0; nf < 4; ++nf){
          float v = (acc[mi][nf][j] + kb[nf])*ks[nf] + kbe[nf];
          v = fmaxf(v, 0.f);
          int co = wc*64 + nf*16 + fr;
          *(unsigned short*)(lds + px*256 + ((co*2) ^ (((px>>2)&7)<<4))) = f2bf(v);
        }
      }
  }
  __syncthreads();
  {
    int p = tid>>1, half = tid&1;
    int r = rg*4 + (p>>5), c = p&31;
    unsigned short* dst;
    if(mode == 0) dst = outp + ((size_t)n*PPIX + (r+1)*PW2 + (c+1))*128 + half*64;
    else          dst = outp + ((size_t)n*HWPIX + rg*128 + p)*128 + half*64;
    #pragma unroll
    for(int s = 0; s < 8; ++s){
      int slot = half*8 + s;
      uint4 v = *(uint4*)(lds + p*256 + ((slot*16) ^ (((p>>2)&7)<<4)));
      *(uint4*)(dst + s*8) = v;
    }
  }
  if(mode == 1){
    int co = tid & 127, g = tid>>7;
    float sum = 0.f;
    #pragma unroll 8
    for(int i = 0; i < 64; ++i){
      int px = g*64 + i;
      sum += bf2f(*(unsigned short*)(lds + px*256 + ((co*2) ^ (((px>>2)&7)<<4))));
    }
    atomicAdd(&xnode_acc[n*HIDC + co], sum);
  }
}

// ---------------- GAT linear: h = x@lin, plus per-head attn dots ------------
__global__ void k_gat_lin(const float* __restrict__ xin, float scale,
                          const float* __restrict__ lin,
                          const float* __restrict__ as_, const float* __restrict__ ad_,
                          float* __restrict__ h, float* __restrict__ a_s, float* __restrict__ a_d){
  __shared__ float xs[128];
  __shared__ float rs0[4], rs1[4], rd0[4], rd1[4];
  int n = blockIdx.x, t = threadIdx.x;
  if(t < 128) xs[t] = xin[n*128 + t]*scale;
  __syncthreads();
  float o0 = 0.f, o1 = 0.f;
  for(int k = 0; k < 128; ++k){
    float xv = xs[k];
    o0 += xv*lin[k*512 + t];
    o1 += xv*lin[k*512 + t + 256];
  }
  h[(size_t)n*512 + t] = o0;
  h[(size_t)n*512 + t + 256] = o1;
  float s0 = o0*as_[t], s1 = o1*as_[t+256];
  float d0 = o0*ad_[t], d1 = o1*ad_[t+256];
  #pragma unroll
  for(int o = 32; o; o >>= 1){
    s0 += __shfl_down(s0, o); s1 += __shfl_down(s1, o);
    d0 += __shfl_down(d0, o); d1 += __shfl_down(d1, o);
  }
  int w = t>>6;
  if((t&63) == 0){ rs0[w]=s0; rs1[w]=s1; rd0[w]=d0; rd1[w]=d1; }
  __syncthreads();
  if(t < 4){
    if(t < 2){
      a_s[n*4+t] = rs0[2*t] + rs0[2*t+1];
      a_d[n*4+t] = rd0[2*t] + rd0[2*t+1];
    } else {
      a_s[n*4+t] = rs1[2*(t-2)] + rs1[2*(t-2)+1];
      a_d[n*4+t] = rd1[2*(t-2)] + rd1[2*(t-2)+1];
    }
  }
}

// ---------------- GAT aggregate: per-dst softmax + weighted sum -------------
__global__ void k_gat_aggr(const int* __restrict__ offs, const int* __restrict__ csr_src,
                           const float* __restrict__ a_s, const float* __restrict__ a_d,
                           const float* __restrict__ h, const float* __restrict__ bias,
                           float* __restrict__ y){
  __shared__ int ssrc[2048];
  __shared__ float sex[4][2048];
  __shared__ float out4[512];
  __shared__ float adn[4], smax[4], sden[4];
  __shared__ float wred[4][4];
  int n = blockIdx.x, t = threadIdx.x;
  int base = offs[n], deg = offs[n+1] - base;
  if(t < 4) adn[t] = a_d[n*4 + t];
  __syncthreads();
  bool cached = (deg <= 2048);
  float lm0=-1e30f, lm1=-1e30f, lm2=-1e30f, lm3=-1e30f;
  for(int e = t; e < deg; e += 256){
    int s = csr_src[base + e];
    float v0 = a_s[s*4+0] + adn[0]; v0 = v0 > 0.f ? v0 : 0.2f*v0;
    float v1 = a_s[s*4+1] + adn[1]; v1 = v1 > 0.f ? v1 : 0.2f*v1;
    float v2 = a_s[s*4+2] + adn[2]; v2 = v2 > 0.f ? v2 : 0.2f*v2;
    float v3 = a_s[s*4+3] + adn[3]; v3 = v3 > 0.f ? v3 : 0.2f*v3;
    if(cached){ ssrc[e]=s; sex[0][e]=v0; sex[1][e]=v1; sex[2][e]=v2; sex[3][e]=v3; }
    lm0 = fmaxf(lm0, v0); lm1 = fmaxf(lm1, v1); lm2 = fmaxf(lm2, v2); lm3 = fmaxf(lm3, v3);
  }
  #pragma unroll
  for(int o = 32; o; o >>= 1){
    lm0 = fmaxf(lm0, __shfl_down(lm0, o)); lm1 = fmaxf(lm1, __shfl_down(lm1, o));
    lm2 = fmaxf(lm2, __shfl_down(lm2, o)); lm3 = fmaxf(lm3, __shfl_down(lm3, o));
  }
  int w = t>>6;
  if((t&63) == 0){ wred[w][0]=lm0; wred[w][1]=lm1; wred[w][2]=lm2; wred[w][3]=lm3; }
  __syncthreads();
  if(t < 4) smax[t] = fmaxf(fmaxf(wred[0][t], wred[1][t]), fmaxf(wred[2][t], wred[3][t]));
  __syncthreads();
  float m0 = smax[0], m1 = smax[1], m2 = smax[2], m3 = smax[3];
  float ls0=0.f, ls1=0.f, ls2=0.f, ls3=0.f;
  for(int e = t; e < deg; e += 256){
    float e0, e1, e2, e3;
    if(cached){ e0 = sex[0][e]; e1 = sex[1][e]; e2 = sex[2][e]; e3 = sex[3][e]; }
    else {
      int s = csr_src[base + e];
      e0 = a_s[s*4+0] + adn[0]; e0 = e0 > 0.f ? e0 : 0.2f*e0;
      e1 = a_s[s*4+1] + adn[1]; e1 = e1 > 0.f ? e1 : 0.2f*e1;
      e2 = a_s[s*4+2] + adn[2]; e2 = e2 > 0.f ? e2 : 0.2f*e2;
      e3 = a_s[s*4+3] + adn[3]; e3 = e3 > 0.f ? e3 : 0.2f*e3;
    }
    e0 = __expf(e0-m0); e1 = __expf(e1-m1); e2 = __expf(e2-m2); e3 = __expf(e3-m3);
    if(cached){ sex[0][e]=e0; sex[1][e]=e1; sex[2][e]=e2; sex[3][e]=e3; }
    ls0 += e0; ls1 += e1; ls2 += e2; ls3 += e3;
  }
  #pragma unroll
  for(int o = 32; o; o >>= 1){
    ls0 += __shfl_down(ls0, o); ls1 += __shfl_down(ls1, o);
    ls2 += __shfl_down(ls2, o); ls3 += __shfl_down(ls3, o);
  }
  __syncthreads();   // wred(max) fully consumed
  if((t&63) == 0){ wred[w][0]=ls0; wred[w][1]=ls1; wred[w][2]=ls2; wred[w][3]=ls3; }
  __syncthreads();
  if(t < 4) sden[t] = wred[0][t] + wred[1][t] + wred[2][t] + wred[3][t] + 1e-16f;
  __syncthreads();
  #pragma unroll
  for(int oo = 0; oo < 2; ++oo){
    int o = t + oo*256;
    int hd = o>>7, d = o&127;
    float mh = smax[hd];
    float accv = 0.f;
    for(int e = 0; e < deg; ++e){
      float ex; int s;
      if(cached){ ex = sex[hd][e]; s = ssrc[e]; }
      else {
        s = csr_src[base + e];
        float v = a_s[s*4+hd] + adn[hd]; v = v > 0.f ? v : 0.2f*v;
        ex = __expf(v - mh);
      }
      accv += ex * h[(size_t)s*512 + hd*128 + d];
    }
    out4[o] = accv / sden[hd];
  }
  __syncthreads();
  if(t < 128){
    float v = (out4[t] + out4[128+t] + out4[256+t] + out4[384+t])*0.25f + bias[t];
    y[n*128 + t] = fmaxf(v, 0.f);
  }
}

// ---------------- per-node bias for final conv: nb = op_w @ xg2 + op_b ------
__global__ void k_nodebias(const float* __restrict__ xg2, const float* __restrict__ op_w,
                           const float* __restrict__ op_b, float* __restrict__ nb){
  int g = blockIdx.x*256 + threadIdx.x;
  if(g < NIMG*64){
    int n = g>>6, co = g&63;
    float acc = op_b[co];
    for(int k = 0; k < 128; ++k) acc += op_w[co*128+k]*xg2[n*128+k];
    nb[g] = acc;
  }
}

// ---------------- final 1x1 conv: out = op_w@xp2 + nb, NCHW f32 -------------
__launch_bounds__(256, 2)
__global__ void k_outconv(const unsigned short* __restrict__ xp2,
                          const unsigned short* __restrict__ Wop,
                          const float* __restrict__ nb, float* __restrict__ out){
  __shared__ char lds[16384];
  int tid = threadIdx.x;
  int n = blockIdx.x>>3, rg = blockIdx.x&7;
  #pragma unroll
  for(int it = 0; it < 4; ++it){
    uint4 v = *(const uint4*)((const char*)Wop + it*4096 + tid*16);
    *(uint4*)(lds + it*4096 + tid*16) = v;
  }
  __syncthreads();
  int wid = tid>>6, lane = tid&63;
  int wr = wid>>1, wc = wid&1, fr = lane&15, fq = lane>>4;
  f32x4 acc[4][2];
  #pragma unroll
  for(int a = 0; a < 4; ++a){ acc[a][0] = (f32x4){0.f,0.f,0.f,0.f}; acc[a][1] = (f32x4){0.f,0.f,0.f,0.f}; }
  const unsigned short* abase = xp2 + ((size_t)n*HWPIX + rg*128)*128;
  #pragma unroll
  for(int kc = 0; kc < 4; ++kc){
    bf16x8 af[4], bfr[2];
    #pragma unroll
    for(int mi = 0; mi < 4; ++mi){
      int p = wr*64 + mi*16 + fr;
      af[mi] = *(const bf16x8*)(abase + p*128 + kc*32 + fq*8);
    }
    #pragma unroll
    for(int nf = 0; nf < 2; ++nf){
      int co = wc*32 + nf*16 + fr;
      int slot = (kc*4 + fq) ^ (co&7);
      bfr[nf] = *(const bf16x8*)(lds + co*256 + slot*16);
    }
    #pragma unroll
    for(int mi = 0; mi < 4; ++mi)
      #pragma unroll
      for(int nf = 0; nf < 2; ++nf)
        acc[mi][nf] = __builtin_amdgcn_mfma_f32_16x16x32_bf16(af[mi], bfr[nf], acc[mi][nf], 0,0,0);
  }
  #pragma unroll
  for(int mi = 0; mi < 4; ++mi)
    #pragma unroll
    for(int nf = 0; nf < 2; ++nf){
      int co = wc*32 + nf*16 + fr;
      int hw = rg*128 + wr*64 + mi*16 + fq*4;
      float nbv = nb[n*64 + co];
      float4 v = { acc[mi][nf][0]+nbv, acc[mi][nf][1]+nbv, acc[mi][nf][2]+nbv, acc[mi][nf][3]+nbv };
      *(float4*)(out + ((size_t)n*64 + co)*HWPIX + hw) = v;
    }
}

// ---------------- host launch ----------------------------------------------
extern "C" void kernel_launch(void* const* d_in, const int* in_sizes, int n_in,
                              void* d_out, int out_size, void* d_ws, size_t ws_size,
                              hipStream_t stream){
  const float* x       = (const float*)d_in[0];
  const int*   ei      = (const int*)d_in[1];
  const float* conf    = (const float*)d_in[2];
  const float* fe_w    = (const float*)d_in[3];
  const float* fe_b    = (const float*)d_in[4];
  const float* fe_g    = (const float*)d_in[5];
  const float* fe_beta = (const float*)d_in[6];
  const float* sp_w1   = (const float*)d_in[7];
  const float* sp_b1   = (const float*)d_in[8];
  const float* sp_g1   = (const float*)d_in[9];
  const float* sp_be1  = (const float*)d_in[10];
  const float* sp_w2   = (const float*)d_in[11];
  const float* sp_b2   = (const float*)d_in[12];
  const float* sp_g2   = (const float*)d_in[13];
  const float* sp_be2  = (const float*)d_in[14];
  const float* g1_lin  = (const float*)d_in[15];
  const float* g1_as   = (const float*)d_in[16];
  const float* g1_ad   = (const float*)d_in[17];
  const float* g1_b    = (const float*)d_in[18];
  const float* g2_lin  = (const float*)d_in[19];
  const float* g2_as   = (const float*)d_in[20];
  const float* g2_ad   = (const float*)d_in[21];
  const float* g2_b    = (const float*)d_in[22];
  const float* op_w    = (const float*)d_in[23];
  const float* op_b    = (const float*)d_in[24];
  float* out = (float*)d_out;

  char* ws = (char*)d_ws;
  size_t off = 0;
  auto alloc = [&](size_t bytes)->char*{
    char* p = ws + off; off += (bytes + 255) & ~(size_t)255; return p;
  };
  unsigned short* bigA  = (unsigned short*)alloc((size_t)NIMG*PPIX*128*2); // xe_pad, later xp2
  unsigned short* xp1   = (unsigned short*)alloc((size_t)NIMG*PPIX*128*2);
  unsigned short* Wb1   = (unsigned short*)alloc(147456*2);
  unsigned short* Wb2   = (unsigned short*)alloc(147456*2);
  unsigned short* Wfe   = (unsigned short*)alloc(8192*2);
  unsigned short* Wop   = (unsigned short*)alloc(8192*2);
  float* xnode_acc = (float*)alloc(NIMG*HIDC*4);
  float* h     = (float*)alloc((size_t)NIMG*512*4);
  float* a_s   = (float*)alloc(NIMG*4*4);
  float* a_d   = (float*)alloc(NIMG*4*4);
  float* xg1   = (float*)alloc(NIMG*HIDC*4);
  float* xg2   = (float*)alloc(NIMG*HIDC*4);
  int* cnt     = (int*)alloc(NIMG*4);
  int* pos     = (int*)alloc(NIMG*4);
  int* offs    = (int*)alloc((NIMG+1)*4);
  int* csr_src = (int*)alloc((NEDGE+NIMG)*4);
  float* nb    = (float*)alloc(NIMG*64*4);
  if(off > ws_size) return;   // workspace too small — bail cleanly
  unsigned short* xp2 = bigA; // reuse region A after conv1 consumed xe

  k_init<<<1024, 256, 0, stream>>>(bigA, xp1, xnode_acc, cnt, pos);
  k_wconv<<<576, 256, 0, stream>>>(sp_w1, sp_w2, fe_w, op_w, Wb1, Wb2, Wfe, Wop);
  k_csr_count<<<(NEDGE+255)/256, 256, 0, stream>>>(ei, cnt);
  k_csr_scan<<<1, 512, 0, stream>>>(cnt, offs);
  k_csr_fill<<<(NEDGE+NIMG+255)/256, 256, 0, stream>>>(ei, offs, pos, csr_src);
  k_encode<<<4096, 256, 0, stream>>>(x, conf, Wfe, fe_b, fe_g, fe_beta, bigA);
  k_conv3<<<4096, 256, 0, stream>>>(bigA, Wb1, sp_b1, sp_g1, sp_be1, xp1, xnode_acc, 0);
  k_conv3<<<4096, 256, 0, stream>>>(xp1, Wb2, sp_b2, sp_g2, sp_be2, xp2, xnode_acc, 1);
  k_gat_lin<<<512, 256, 0, stream>>>(xnode_acc, 1.f/1024.f, g1_lin, g1_as, g1_ad, h, a_s, a_d);
  k_gat_aggr<<<512, 256, 0, stream>>>(offs, csr_src, a_s, a_d, h, g1_b, xg1);
  k_gat_lin<<<512, 256, 0, stream>>>(xg1, 1.f, g2_lin, g2_as, g2_ad, h, a_s, a_d);
  k_gat_aggr<<<512, 256, 0, stream>>>(offs, csr_src, a_s, a_d, h, g2_b, xg2);
  k_nodebias<<<(NIMG*64+255)/256, 256, 0, stream>>>(xg2, op_w, op_b, nb);
  k_outconv<<<4096, 256, 0, stream>>>(xp2, Wop, nb, out);
}

// Round 2
// 907.341 us; speedup vs baseline: 1.0213x; 1.0213x over previous
//
#include <hip/hip_runtime.h>
#include <stdint.h>

#define NIMG 512
#define CINCH 64
#define HIDC 128
#define NEDGE 16384
#define HWPIX 1024
#define PW2 34
#define PPIX 1156   // 34*34

typedef __attribute__((ext_vector_type(8))) short bf16x8;
typedef __attribute__((ext_vector_type(4))) float f32x4;

static __device__ __forceinline__ unsigned short f2bf(float f){
  unsigned u = __builtin_bit_cast(unsigned, f);
  u += 0x7FFFu + ((u>>16)&1u);
  return (unsigned short)(u>>16);
}
static __device__ __forceinline__ float bf2f(unsigned short s){
  unsigned u = ((unsigned)s)<<16;
  return __builtin_bit_cast(float, u);
}

// ---------------- init: zero pad borders + accumulators + csr counters ------
__global__ void k_init(unsigned short* xe_pad, unsigned short* xp1_pad,
                       float* xnode_acc, int* cnt, int* pos){
  int idx = blockIdx.x*256 + threadIdx.x;
  int total_b = NIMG*132*16;
  for(int i = idx; i < total_b; i += gridDim.x*256){
    int img = i / (132*16);
    int rem = i - img*(132*16);
    int bp = rem >> 4;
    int slot = rem & 15;
    int r, c;
    if(bp < 34){ r = 0; c = bp; }
    else if(bp < 68){ r = 33; c = bp-34; }
    else if(bp < 100){ r = bp-68+1; c = 0; }
    else { r = bp-100+1; c = 33; }
    size_t off = ((size_t)img*PPIX + r*PW2 + c)*128 + slot*8;
    uint4 z = {0,0,0,0};
    *(uint4*)(xe_pad + off) = z;
    *(uint4*)(xp1_pad + off) = z;
  }
  for(int i = idx; i < NIMG*HIDC; i += gridDim.x*256) xnode_acc[i] = 0.f;
  for(int i = idx; i < NIMG; i += gridDim.x*256){ cnt[i] = 0; pos[i] = 0; }
}

// ---------------- weight conversion to pre-swizzled bf16 LDS images ---------
// LDS image row (256B or 128B): slot s holds input-channel group (s ^ (co&7))
__global__ void k_wconv(const float* __restrict__ sp_w1, const float* __restrict__ sp_w2,
                        const float* __restrict__ fe_w, const float* __restrict__ op_w,
                        unsigned short* Wb1, unsigned short* Wb2,
                        unsigned short* Wfe, unsigned short* Wop){
  int idx = blockIdx.x*256 + threadIdx.x;
  for(int i = idx; i < 147456; i += gridDim.x*256){
    int j = i & 7, s = (i>>3)&15, co = (i>>7)&127, tap = i>>14;
    int cin = ((s ^ (co&7))<<3) + j;
    Wb1[i] = f2bf(sp_w1[(co*128+cin)*9 + tap]);
    Wb2[i] = f2bf(sp_w2[(co*128+cin)*9 + tap]);
  }
  for(int i = idx; i < 8192; i += gridDim.x*256){
    int j = i & 7, s = (i>>3)&7, co = i>>6;
    int ci = ((s ^ (co&7))<<3) + j;
    Wfe[i] = f2bf(fe_w[co*64+ci]);
  }
  for(int i = idx; i < 8192; i += gridDim.x*256){
    int j = i & 7, s = (i>>3)&15, co = i>>7;   // co 0..63
    int cin = ((s ^ (co&7))<<3) + j;
    Wop[i] = f2bf(op_w[co*128+cin]);
  }
}

// ---------------- CSR build ------------------------------------------------
__global__ void k_csr_count(const int* __restrict__ ei, int* cnt){
  int e = blockIdx.x*256 + threadIdx.x;
  if(e < NEDGE) atomicAdd(&cnt[ei[NEDGE+e]], 1);
}
__global__ void k_csr_scan(const int* __restrict__ cnt, int* offs){
  __shared__ int sc[512];
  int t = threadIdx.x;
  sc[t] = cnt[t] + 1;   // +1 for self loop
  __syncthreads();
  for(int o = 1; o < 512; o <<= 1){
    int add = (t >= o) ? sc[t-o] : 0;
    __syncthreads();
    sc[t] += add;
    __syncthreads();
  }
  if(t == 0) offs[0] = 0;
  offs[t+1] = sc[t];
}
__global__ void k_csr_fill(const int* __restrict__ ei, const int* __restrict__ offs,
                           int* pos, int* csr_src){
  int e = blockIdx.x*256 + threadIdx.x;
  if(e < NEDGE + NIMG){
    int s, d;
    if(e < NEDGE){ s = ei[e]; d = ei[NEDGE+e]; }
    else { s = e - NEDGE; d = s; }
    int slot = offs[d] + atomicAdd(&pos[d], 1);
    csr_src[slot] = s;
  }
}

// ---------------- encode: 1x1 conv + BN + relu + conf, write padded NHWC ----
__launch_bounds__(256, 2)
__global__ void k_encode(const float* __restrict__ x, const float* __restrict__ conf,
                         const unsigned short* __restrict__ Wfe,
                         const float* __restrict__ fe_b, const float* __restrict__ fe_g,
                         const float* __restrict__ fe_beta,
                         unsigned short* __restrict__ xe_pad){
  __shared__ char lds[49152];          // xa 32KB (f32 swizzled) + wb 16KB
  char* xa = lds; char* wb = lds + 32768;
  int tid = threadIdx.x;
  int n = blockIdx.x >> 3, rg = blockIdx.x & 7;
  int hw0 = rg*128;
  {
    int q = tid >> 3, c0 = tid & 7;
    const float* xb = x + (size_t)n*CINCH*HWPIX + hw0;
    #pragma unroll
    for(int cc = 0; cc < 8; ++cc){
      int c = cc*8 + c0;
      float4 v = *(const float4*)(xb + (size_t)c*HWPIX + q*4);
      float vv[4] = {v.x, v.y, v.z, v.w};
      #pragma unroll
      for(int i = 0; i < 4; ++i){
        int p = q*4 + i;
        *(float*)(xa + p*256 + ((cc ^ (p&7))*32) + c0*4) = vv[i];
      }
    }
    #pragma unroll
    for(int it = 0; it < 4; ++it){
      uint4 w = *(const uint4*)((const char*)Wfe + it*4096 + tid*16);
      *(uint4*)(wb + it*4096 + tid*16) = w;
    }
  }
  __syncthreads();
  int wid = tid>>6, lane = tid&63;
  int wr = wid>>1, wc = wid&1, fr = lane&15, fq = lane>>4;
  f32x4 acc[4][4];
  #pragma unroll
  for(int a = 0; a < 4; ++a)
    #pragma unroll
    for(int b = 0; b < 4; ++b) acc[a][b] = (f32x4){0.f,0.f,0.f,0.f};
  #pragma unroll
  for(int kc = 0; kc < 2; ++kc){
    bf16x8 af[4], bfr[4];
    #pragma unroll
    for(int mi = 0; mi < 4; ++mi){
      int p = wr*64 + mi*16 + fr;
      int u = kc*4 + fq;
      const float* src = (const float*)(xa + p*256 + ((u ^ (p&7))*32));
      float4 lo = *(const float4*)src;
      float4 hi = *(const float4*)(src+4);
      bf16x8 a;
      a[0]=(short)f2bf(lo.x); a[1]=(short)f2bf(lo.y); a[2]=(short)f2bf(lo.z); a[3]=(short)f2bf(lo.w);
      a[4]=(short)f2bf(hi.x); a[5]=(short)f2bf(hi.y); a[6]=(short)f2bf(hi.z); a[7]=(short)f2bf(hi.w);
      af[mi] = a;
    }
    #pragma unroll
    for(int nf = 0; nf < 4; ++nf){
      int co = wc*64 + nf*16 + fr;
      int slot = (kc*4 + fq) ^ (co&7);
      bfr[nf] = *(const bf16x8*)(wb + co*128 + slot*16);
    }
    #pragma unroll
    for(int mi = 0; mi < 4; ++mi)
      #pragma unroll
      for(int nf = 0; nf < 4; ++nf)
        acc[mi][nf] = __builtin_amdgcn_mfma_f32_16x16x32_bf16(af[mi], bfr[nf], acc[mi][nf], 0,0,0);
  }
  __syncthreads();
  {
    const float rs = 0.9999950000374997f;
    float kb[4], ks[4], kbe[4];
    #pragma unroll
    for(int nf = 0; nf < 4; ++nf){
      int co = wc*64 + nf*16 + fr;
      kb[nf] = fe_b[co]; ks[nf] = fe_g[co]*rs; kbe[nf] = fe_beta[co];
    }
    #pragma unroll
    for(int mi = 0; mi < 4; ++mi)
      #pragma unroll
      for(int j = 0; j < 4; ++j){
        int px = wr*64 + mi*16 + fq*4 + j;
        float cf = conf[(size_t)n*HWPIX + hw0 + px];
        #pragma unroll
        for(int nf = 0; nf < 4; ++nf){
          float v = (acc[mi][nf][j] + kb[nf])*ks[nf] + kbe[nf];
          v = fmaxf(v, 0.f)*cf;
          int co = wc*64 + nf*16 + fr;
          *(unsigned short*)(xa + px*256 + ((co*2) ^ (((px>>2)&7)<<4))) = f2bf(v);
        }
      }
  }
  __syncthreads();
  {
    int p = tid>>1, half = tid&1;
    int r = rg*4 + (p>>5), c = p&31;
    unsigned short* dst = xe_pad + ((size_t)n*PPIX + (r+1)*PW2 + (c+1))*128 + half*64;
    #pragma unroll
    for(int s = 0; s < 8; ++s){
      int slot = half*8 + s;
      uint4 v = *(uint4*)(xa + p*256 + ((slot*16) ^ (((p>>2)&7)<<4)));
      *(uint4*)(dst + s*8) = v;
    }
  }
}

// ---------------- 3x3 conv: A-tile in LDS + W double-buffer, 9 shifted GEMMs
// LDS: [0, 55488)    A tile: 204 pixels (6 padded rows x 34 cols) x 272B
//                    (256B of channels + 16B pad -> conflict-free ds_read_b128)
//      [55488,+64KB) W double buffer (2 x 32KB), also epilogue scratch
__launch_bounds__(256, 1)
__global__ void k_conv3(const unsigned short* __restrict__ inp,   // padded NHWC bf16
                        const unsigned short* __restrict__ Wb,    // [9][128][16slots][8] pre-swizzled
                        const float* __restrict__ bnb, const float* __restrict__ bng,
                        const float* __restrict__ bnbe,
                        unsigned short* __restrict__ outp,
                        float* __restrict__ xnode_acc, int mode){  // 0: padded out, 1: flat out + xnode
  extern __shared__ char lds[];
  char* Ab = lds;
  char* Wd = lds + 55488;
  int tid = threadIdx.x;
  int n = blockIdx.x>>3, rg = blockIdx.x&7;

  // ---- stage A tile (3264 granules of 16B) + W tap0 ----
  const char* asrc = (const char*)(inp + ((size_t)n*PPIX + (size_t)rg*4*PW2)*128);
  const char* wsrc = (const char*)Wb;
  uint4 av[13];
  #pragma unroll
  for(int it = 0; it < 13; ++it){
    int i = tid + it*256;
    if(it < 12 || i < 3264) av[it] = *(const uint4*)(asrc + (size_t)i*16);
  }
  uint4 st[8];
  #pragma unroll
  for(int it = 0; it < 8; ++it) st[it] = *(const uint4*)(wsrc + it*4096 + tid*16);
  #pragma unroll
  for(int it = 0; it < 13; ++it){
    int i = tid + it*256;
    if(it < 12 || i < 3264) *(uint4*)(Ab + (i>>4)*272 + (i&15)*16) = av[it];
  }
  #pragma unroll
  for(int it = 0; it < 8; ++it) *(uint4*)(Wd + it*4096 + tid*16) = st[it];
  __syncthreads();

  int wid = tid>>6, lane = tid&63;
  int wr = wid>>1, wc = wid&1, fr = lane&15, fq = lane>>4;
  int pixb[4];
  #pragma unroll
  for(int mi = 0; mi < 4; ++mi){
    int p = wr*64 + mi*16 + fr;
    pixb[mi] = ((p>>5)+1)*PW2 + (p&31) + 1;
  }
  f32x4 acc[4][4];
  #pragma unroll
  for(int a = 0; a < 4; ++a)
    #pragma unroll
    for(int b = 0; b < 4; ++b) acc[a][b] = (f32x4){0.f,0.f,0.f,0.f};

  for(int tap = 0; tap < 9; ++tap){
    char* cur = Wd + (tap&1)*32768;
    int dy = tap/3 - 1, dx = tap - (tap/3)*3 - 1;
    int pd = dy*PW2 + dx;
    if(tap < 8){
      #pragma unroll
      for(int it = 0; it < 8; ++it)
        st[it] = *(const uint4*)(wsrc + (size_t)(tap+1)*32768 + it*4096 + tid*16);
    }
    #pragma unroll
    for(int kc = 0; kc < 4; ++kc){
      bf16x8 af[4], bfr[4];
      #pragma unroll
      for(int mi = 0; mi < 4; ++mi)
        af[mi] = *(const bf16x8*)(Ab + (pixb[mi]+pd)*272 + kc*64 + fq*16);
      #pragma unroll
      for(int nf = 0; nf < 4; ++nf){
        int co = wc*64 + nf*16 + fr;
        int slot = (kc*4 + fq) ^ (co&7);
        bfr[nf] = *(const bf16x8*)(cur + co*256 + slot*16);
      }
      #pragma unroll
      for(int mi = 0; mi < 4; ++mi)
        #pragma unroll
        for(int nf = 0; nf < 4; ++nf)
          acc[mi][nf] = __builtin_amdgcn_mfma_f32_16x16x32_bf16(af[mi], bfr[nf], acc[mi][nf], 0,0,0);
    }
    if(tap < 8){
      char* nxt = Wd + ((tap+1)&1)*32768;
      #pragma unroll
      for(int it = 0; it < 8; ++it) *(uint4*)(nxt + it*4096 + tid*16) = st[it];
    }
    __syncthreads();
  }
  // epilogue: BN + relu -> LDS transpose (in W region) -> coalesced store
  char* eb = Wd;
  {
    const float rs = 0.9999950000374997f;
    float kb[4], ks[4], kbe[4];
    #pragma unroll
    for(int nf = 0; nf < 4; ++nf){
      int co = wc*64 + nf*16 + fr;
      kb[nf] = bnb[co]; ks[nf] = bng[co]*rs; kbe[nf] = bnbe[co];
    }
    #pragma unroll
    for(int mi = 0; mi < 4; ++mi)
      #pragma unroll
      for(int j = 0; j < 4; ++j){
        int px = wr*64 + mi*16 + fq*4 + j;
        #pragma unroll
        for(int nf = 0; nf < 4; ++nf){
          float v = (acc[mi][nf][j] + kb[nf])*ks[nf] + kbe[nf];
          v = fmaxf(v, 0.f);
          int co = wc*64 + nf*16 + fr;
          *(unsigned short*)(eb + px*256 + ((co*2) ^ (((px>>2)&7)<<4))) = f2bf(v);
        }
      }
  }
  __syncthreads();
  {
    int p = tid>>1, half = tid&1;
    int r = rg*4 + (p>>5), c = p&31;
    unsigned short* dst;
    if(mode == 0) dst = outp + ((size_t)n*PPIX + (r+1)*PW2 + (c+1))*128 + half*64;
    else          dst = outp + ((size_t)n*HWPIX + rg*128 + p)*128 + half*64;
    #pragma unroll
    for(int s = 0; s < 8; ++s){
      int slot = half*8 + s;
      uint4 v = *(uint4*)(eb + p*256 + ((slot*16) ^ (((p>>2)&7)<<4)));
      *(uint4*)(dst + s*8) = v;
    }
  }
  if(mode == 1){
    int co = tid & 127, g = tid>>7;
    float sum = 0.f;
    #pragma unroll 8
    for(int i = 0; i < 64; ++i){
      int px = g*64 + i;
      sum += bf2f(*(unsigned short*)(eb + px*256 + ((co*2) ^ (((px>>2)&7)<<4))));
    }
    atomicAdd(&xnode_acc[n*HIDC + co], sum);
  }
}

// ---------------- GAT linear: h = x@lin, plus per-head attn dots ------------
__global__ void k_gat_lin(const float* __restrict__ xin, float scale,
                          const float* __restrict__ lin,
                          const float* __restrict__ as_, const float* __restrict__ ad_,
                          float* __restrict__ h, float* __restrict__ a_s, float* __restrict__ a_d){
  __shared__ float xs[128];
  __shared__ float rs0[4], rs1[4], rd0[4], rd1[4];
  int n = blockIdx.x, t = threadIdx.x;
  if(t < 128) xs[t] = xin[n*128 + t]*scale;
  __syncthreads();
  float o0 = 0.f, o1 = 0.f;
  for(int k = 0; k < 128; ++k){
    float xv = xs[k];
    o0 += xv*lin[k*512 + t];
    o1 += xv*lin[k*512 + t + 256];
  }
  h[(size_t)n*512 + t] = o0;
  h[(size_t)n*512 + t + 256] = o1;
  float s0 = o0*as_[t], s1 = o1*as_[t+256];
  float d0 = o0*ad_[t], d1 = o1*ad_[t+256];
  #pragma unroll
  for(int o = 32; o; o >>= 1){
    s0 += __shfl_down(s0, o); s1 += __shfl_down(s1, o);
    d0 += __shfl_down(d0, o); d1 += __shfl_down(d1, o);
  }
  int w = t>>6;
  if((t&63) == 0){ rs0[w]=s0; rs1[w]=s1; rd0[w]=d0; rd1[w]=d1; }
  __syncthreads();
  if(t < 4){
    if(t < 2){
      a_s[n*4+t] = rs0[2*t] + rs0[2*t+1];
      a_d[n*4+t] = rd0[2*t] + rd0[2*t+1];
    } else {
      a_s[n*4+t] = rs1[2*(t-2)] + rs1[2*(t-2)+1];
      a_d[n*4+t] = rd1[2*(t-2)] + rd1[2*(t-2)+1];
    }
  }
}

// ---------------- GAT aggregate: per-dst softmax + weighted sum -------------
__global__ void k_gat_aggr(const int* __restrict__ offs, const int* __restrict__ csr_src,
                           const float* __restrict__ a_s, const float* __restrict__ a_d,
                           const float* __restrict__ h, const float* __restrict__ bias,
                           float* __restrict__ y){
  __shared__ int ssrc[2048];
  __shared__ float sex[4][2048];
  __shared__ float out4[512];
  __shared__ float adn[4], smax[4], sden[4];
  __shared__ float wred[4][4];
  int n = blockIdx.x, t = threadIdx.x;
  int base = offs[n], deg = offs[n+1] - base;
  if(t < 4) adn[t] = a_d[n*4 + t];
  __syncthreads();
  bool cached = (deg <= 2048);
  float lm0=-1e30f, lm1=-1e30f, lm2=-1e30f, lm3=-1e30f;
  for(int e = t; e < deg; e += 256){
    int s = csr_src[base + e];
    float v0 = a_s[s*4+0] + adn[0]; v0 = v0 > 0.f ? v0 : 0.2f*v0;
    float v1 = a_s[s*4+1] + adn[1]; v1 = v1 > 0.f ? v1 : 0.2f*v1;
    float v2 = a_s[s*4+2] + adn[2]; v2 = v2 > 0.f ? v2 : 0.2f*v2;
    float v3 = a_s[s*4+3] + adn[3]; v3 = v3 > 0.f ? v3 : 0.2f*v3;
    if(cached){ ssrc[e]=s; sex[0][e]=v0; sex[1][e]=v1; sex[2][e]=v2; sex[3][e]=v3; }
    lm0 = fmaxf(lm0, v0); lm1 = fmaxf(lm1, v1); lm2 = fmaxf(lm2, v2); lm3 = fmaxf(lm3, v3);
  }
  #pragma unroll
  for(int o = 32; o; o >>= 1){
    lm0 = fmaxf(lm0, __shfl_down(lm0, o)); lm1 = fmaxf(lm1, __shfl_down(lm1, o));
    lm2 = fmaxf(lm2, __shfl_down(lm2, o)); lm3 = fmaxf(lm3, __shfl_down(lm3, o));
  }
  int w = t>>6;
  if((t&63) == 0){ wred[w][0]=lm0; wred[w][1]=lm1; wred[w][2]=lm2; wred[w][3]=lm3; }
  __syncthreads();
  if(t < 4) smax[t] = fmaxf(fmaxf(wred[0][t], wred[1][t]), fmaxf(wred[2][t], wred[3][t]));
  __syncthreads();
  float m0 = smax[0], m1 = smax[1], m2 = smax[2], m3 = smax[3];
  float ls0=0.f, ls1=0.f, ls2=0.f, ls3=0.f;
  for(int e = t; e < deg; e += 256){
    float e0, e1, e2, e3;
    if(cached){ e0 = sex[0][e]; e1 = sex[1][e]; e2 = sex[2][e]; e3 = sex[3][e]; }
    else {
      int s = csr_src[base + e];
      e0 = a_s[s*4+0] + adn[0]; e0 = e0 > 0.f ? e0 : 0.2f*e0;
      e1 = a_s[s*4+1] + adn[1]; e1 = e1 > 0.f ? e1 : 0.2f*e1;
      e2 = a_s[s*4+2] + adn[2]; e2 = e2 > 0.f ? e2 : 0.2f*e2;
      e3 = a_s[s*4+3] + adn[3]; e3 = e3 > 0.f ? e3 : 0.2f*e3;
    }
    e0 = __expf(e0-m0); e1 = __expf(e1-m1); e2 = __expf(e2-m2); e3 = __expf(e3-m3);
    if(cached){ sex[0][e]=e0; sex[1][e]=e1; sex[2][e]=e2; sex[3][e]=e3; }
    ls0 += e0; ls1 += e1; ls2 += e2; ls3 += e3;
  }
  #pragma unroll
  for(int o = 32; o; o >>= 1){
    ls0 += __shfl_down(ls0, o); ls1 += __shfl_down(ls1, o);
    ls2 += __shfl_down(ls2, o); ls3 += __shfl_down(ls3, o);
  }
  __syncthreads();   // wred(max) fully consumed
  if((t&63) == 0){ wred[w][0]=ls0; wred[w][1]=ls1; wred[w][2]=ls2; wred[w][3]=ls3; }
  __syncthreads();
  if(t < 4) sden[t] = wred[0][t] + wred[1][t] + wred[2][t] + wred[3][t] + 1e-16f;
  __syncthreads();
  #pragma unroll
  for(int oo = 0; oo < 2; ++oo){
    int o = t + oo*256;
    int hd = o>>7, d = o&127;
    float mh = smax[hd];
    float accv = 0.f;
    for(int e = 0; e < deg; ++e){
      float ex; int s;
      if(cached){ ex = sex[hd][e]; s = ssrc[e]; }
      else {
        s = csr_src[base + e];
        float v = a_s[s*4+hd] + adn[hd]; v = v > 0.f ? v : 0.2f*v;
        ex = __expf(v - mh);
      }
      accv += ex * h[(size_t)s*512 + hd*128 + d];
    }
    out4[o] = accv / sden[hd];
  }
  __syncthreads();
  if(t < 128){
    float v = (out4[t] + out4[128+t] + out4[256+t] + out4[384+t])*0.25f + bias[t];
    y[n*128 + t] = fmaxf(v, 0.f);
  }
}

// ---------------- per-node bias for final conv: nb = op_w @ xg2 + op_b ------
__global__ void k_nodebias(const float* __restrict__ xg2, const float* __restrict__ op_w,
                           const float* __restrict__ op_b, float* __restrict__ nb){
  int g = blockIdx.x*256 + threadIdx.x;
  if(g < NIMG*64){
    int n = g>>6, co = g&63;
    float acc = op_b[co];
    for(int k = 0; k < 128; ++k) acc += op_w[co*128+k]*xg2[n*128+k];
    nb[g] = acc;
  }
}

// ---------------- final 1x1 conv: out = op_w@xp2 + nb, NCHW f32 -------------
__launch_bounds__(256, 2)
__global__ void k_outconv(const unsigned short* __restrict__ xp2,
                          const unsigned short* __restrict__ Wop,
                          const float* __restrict__ nb, float* __restrict__ out){
  __shared__ char lds[16384];
  int tid = threadIdx.x;
  int n = blockIdx.x>>3, rg = blockIdx.x&7;
  #pragma unroll
  for(int it = 0; it < 4; ++it){
    uint4 v = *(const uint4*)((const char*)Wop + it*4096 + tid*16);
    *(uint4*)(lds + it*4096 + tid*16) = v;
  }
  __syncthreads();
  int wid = tid>>6, lane = tid&63;
  int wr = wid>>1, wc = wid&1, fr = lane&15, fq = lane>>4;
  f32x4 acc[4][2];
  #pragma unroll
  for(int a = 0; a < 4; ++a){ acc[a][0] = (f32x4){0.f,0.f,0.f,0.f}; acc[a][1] = (f32x4){0.f,0.f,0.f,0.f}; }
  const unsigned short* abase = xp2 + ((size_t)n*HWPIX + rg*128)*128;
  #pragma unroll
  for(int kc = 0; kc < 4; ++kc){
    bf16x8 af[4], bfr[2];
    #pragma unroll
    for(int mi = 0; mi < 4; ++mi){
      int p = wr*64 + mi*16 + fr;
      af[mi] = *(const bf16x8*)(abase + p*128 + kc*32 + fq*8);
    }
    #pragma unroll
    for(int nf = 0; nf < 2; ++nf){
      int co = wc*32 + nf*16 + fr;
      int slot = (kc*4 + fq) ^ (co&7);
      bfr[nf] = *(const bf16x8*)(lds + co*256 + slot*16);
    }
    #pragma unroll
    for(int mi = 0; mi < 4; ++mi)
      #pragma unroll
      for(int nf = 0; nf < 2; ++nf)
        acc[mi][nf] = __builtin_amdgcn_mfma_f32_16x16x32_bf16(af[mi], bfr[nf], acc[mi][nf], 0,0,0);
  }
  #pragma unroll
  for(int mi = 0; mi < 4; ++mi)
    #pragma unroll
    for(int nf = 0; nf < 2; ++nf){
      int co = wc*32 + nf*16 + fr;
      int hw = rg*128 + wr*64 + mi*16 + fq*4;
      float nbv = nb[n*64 + co];
      float4 v = { acc[mi][nf][0]+nbv, acc[mi][nf][1]+nbv, acc[mi][nf][2]+nbv, acc[mi][nf][3]+nbv };
      *(float4*)(out + ((size_t)n*64 + co)*HWPIX + hw) = v;
    }
}

// ---------------- host launch ----------------------------------------------
extern "C" void kernel_launch(void* const* d_in, const int* in_sizes, int n_in,
                              void* d_out, int out_size, void* d_ws, size_t ws_size,
                              hipStream_t stream){
  const float* x       = (const float*)d_in[0];
  const int*   ei      = (const int*)d_in[1];
  const float* conf    = (const float*)d_in[2];
  const float* fe_w    = (const float*)d_in[3];
  const float* fe_b    = (const float*)d_in[4];
  const float* fe_g    = (const float*)d_in[5];
  const float* fe_beta = (const float*)d_in[6];
  const float* sp_w1   = (const float*)d_in[7];
  const float* sp_b1   = (const float*)d_in[8];
  const float* sp_g1   = (const float*)d_in[9];
  const float* sp_be1  = (const float*)d_in[10];
  const float* sp_w2   = (const float*)d_in[11];
  const float* sp_b2   = (const float*)d_in[12];
  const float* sp_g2   = (const float*)d_in[13];
  const float* sp_be2  = (const float*)d_in[14];
  const float* g1_lin  = (const float*)d_in[15];
  const float* g1_as   = (const float*)d_in[16];
  const float* g1_ad   = (const float*)d_in[17];
  const float* g1_b    = (const float*)d_in[18];
  const float* g2_lin  = (const float*)d_in[19];
  const float* g2_as   = (const float*)d_in[20];
  const float* g2_ad   = (const float*)d_in[21];
  const float* g2_b    = (const float*)d_in[22];
  const float* op_w    = (const float*)d_in[23];
  const float* op_b    = (const float*)d_in[24];
  float* out = (float*)d_out;

  char* ws = (char*)d_ws;
  size_t off = 0;
  auto alloc = [&](size_t bytes)->char*{
    char* p = ws + off; off += (bytes + 255) & ~(size_t)255; return p;
  };
  unsigned short* bigA  = (unsigned short*)alloc((size_t)NIMG*PPIX*128*2); // xe_pad, later xp2
  unsigned short* xp1   = (unsigned short*)alloc((size_t)NIMG*PPIX*128*2);
  unsigned short* Wb1   = (unsigned short*)alloc(147456*2);
  unsigned short* Wb2   = (unsigned short*)alloc(147456*2);
  unsigned short* Wfe   = (unsigned short*)alloc(8192*2);
  unsigned short* Wop   = (unsigned short*)alloc(8192*2);
  float* xnode_acc = (float*)alloc(NIMG*HIDC*4);
  float* h     = (float*)alloc((size_t)NIMG*512*4);
  float* a_s   = (float*)alloc(NIMG*4*4);
  float* a_d   = (float*)alloc(NIMG*4*4);
  float* xg1   = (float*)alloc(NIMG*HIDC*4);
  float* xg2   = (float*)alloc(NIMG*HIDC*4);
  int* cnt     = (int*)alloc(NIMG*4);
  int* pos     = (int*)alloc(NIMG*4);
  int* offs    = (int*)alloc((NIMG+1)*4);
  int* csr_src = (int*)alloc((NEDGE+NIMG)*4);
  float* nb    = (float*)alloc(NIMG*64*4);
  if(off > ws_size) return;   // workspace too small — bail cleanly
  unsigned short* xp2 = bigA; // reuse region A after conv1 consumed xe

  // allow 121 KB dynamic LDS for k_conv3 (1 block/CU; LDS/CU = 160 KB)
  hipFuncSetAttribute((const void*)k_conv3,
                      hipFuncAttributeMaxDynamicSharedMemorySize, 121024);

  k_init<<<1024, 256, 0, stream>>>(bigA, xp1, xnode_acc, cnt, pos);
  k_wconv<<<576, 256, 0, stream>>>(sp_w1, sp_w2, fe_w, op_w, Wb1, Wb2, Wfe, Wop);
  k_csr_count<<<(NEDGE+255)/256, 256, 0, stream>>>(ei, cnt);
  k_csr_scan<<<1, 512, 0, stream>>>(cnt, offs);
  k_csr_fill<<<(NEDGE+NIMG+255)/256, 256, 0, stream>>>(ei, offs, pos, csr_src);
  k_encode<<<4096, 256, 0, stream>>>(x, conf, Wfe, fe_b, fe_g, fe_beta, bigA);
  k_conv3<<<4096, 256, 121024, stream>>>(bigA, Wb1, sp_b1, sp_g1, sp_be1, xp1, xnode_acc, 0);
  k_conv3<<<4096, 256, 121024, stream>>>(xp1, Wb2, sp_b2, sp_g2, sp_be2, xp2, xnode_acc, 1);
  k_gat_lin<<<512, 256, 0, stream>>>(xnode_acc, 1.f/1024.f, g1_lin, g1_as, g1_ad, h, a_s, a_d);
  k_gat_aggr<<<512, 256, 0, stream>>>(offs, csr_src, a_s, a_d, h, g1_b, xg1);
  k_gat_lin<<<512, 256, 0, stream>>>(xg1, 1.f, g2_lin, g2_as, g2_ad, h, a_s, a_d);
  k_gat_aggr<<<512, 256, 0, stream>>>(offs, csr_src, a_s, a_d, h, g2_b, xg2);
  k_nodebias<<<(NIMG*64+255)/256, 256, 0, stream>>>(xg2, op_w, op_b, nb);
  k_outconv<<<4096, 256, 0, stream>>>(xp2, Wop, nb, out);
}

// Round 3
// 710.990 us; speedup vs baseline: 1.3033x; 1.2762x over previous
//
#include <hip/hip_runtime.h>
#include <stdint.h>

#define NIMG 512
#define CINCH 64
#define HIDC 128
#define NEDGE 16384
#define HWPIX 1024
#define PW2 34
#define PPIX 1156   // 34*34

typedef __attribute__((ext_vector_type(8))) short bf16x8;
typedef __attribute__((ext_vector_type(4))) float f32x4;

static __device__ __forceinline__ unsigned short f2bf(float f){
  unsigned u = __builtin_bit_cast(unsigned, f);
  u += 0x7FFFu + ((u>>16)&1u);
  return (unsigned short)(u>>16);
}
static __device__ __forceinline__ float bf2f(unsigned short s){
  unsigned u = ((unsigned)s)<<16;
  return __builtin_bit_cast(float, u);
}

// ---------------- init: zero pad borders + accumulators + csr counters ------
__global__ void k_init(unsigned short* xe_pad, unsigned short* xp1_pad,
                       float* xnode_acc, int* cnt, int* pos){
  int idx = blockIdx.x*256 + threadIdx.x;
  int total_b = NIMG*132*16;
  for(int i = idx; i < total_b; i += gridDim.x*256){
    int img = i / (132*16);
    int rem = i - img*(132*16);
    int bp = rem >> 4;
    int slot = rem & 15;
    int r, c;
    if(bp < 34){ r = 0; c = bp; }
    else if(bp < 68){ r = 33; c = bp-34; }
    else if(bp < 100){ r = bp-68+1; c = 0; }
    else { r = bp-100+1; c = 33; }
    size_t off = ((size_t)img*PPIX + r*PW2 + c)*128 + slot*8;
    uint4 z = {0,0,0,0};
    *(uint4*)(xe_pad + off) = z;
    *(uint4*)(xp1_pad + off) = z;
  }
  for(int i = idx; i < NIMG*HIDC; i += gridDim.x*256) xnode_acc[i] = 0.f;
  for(int i = idx; i < NIMG; i += gridDim.x*256){ cnt[i] = 0; pos[i] = 0; }
}

// ---------------- weight conversion to pre-swizzled bf16 LDS images ---------
// LDS image row (256B or 128B): slot s holds input-channel group (s ^ (co&7))
__global__ void k_wconv(const float* __restrict__ sp_w1, const float* __restrict__ sp_w2,
                        const float* __restrict__ fe_w, const float* __restrict__ op_w,
                        unsigned short* Wb1, unsigned short* Wb2,
                        unsigned short* Wfe, unsigned short* Wop){
  int idx = blockIdx.x*256 + threadIdx.x;
  for(int i = idx; i < 147456; i += gridDim.x*256){
    int j = i & 7, s = (i>>3)&15, co = (i>>7)&127, tap = i>>14;
    int cin = ((s ^ (co&7))<<3) + j;
    Wb1[i] = f2bf(sp_w1[(co*128+cin)*9 + tap]);
    Wb2[i] = f2bf(sp_w2[(co*128+cin)*9 + tap]);
  }
  for(int i = idx; i < 8192; i += gridDim.x*256){
    int j = i & 7, s = (i>>3)&7, co = i>>6;
    int ci = ((s ^ (co&7))<<3) + j;
    Wfe[i] = f2bf(fe_w[co*64+ci]);
  }
  for(int i = idx; i < 8192; i += gridDim.x*256){
    int j = i & 7, s = (i>>3)&15, co = i>>7;   // co 0..63
    int cin = ((s ^ (co&7))<<3) + j;
    Wop[i] = f2bf(op_w[co*128+cin]);
  }
}

// ---------------- CSR build ------------------------------------------------
__global__ void k_csr_count(const int* __restrict__ ei, int* cnt){
  int e = blockIdx.x*256 + threadIdx.x;
  if(e < NEDGE) atomicAdd(&cnt[ei[NEDGE+e]], 1);
}
__global__ void k_csr_scan(const int* __restrict__ cnt, int* offs){
  __shared__ int sc[512];
  int t = threadIdx.x;
  sc[t] = cnt[t] + 1;   // +1 for self loop
  __syncthreads();
  for(int o = 1; o < 512; o <<= 1){
    int add = (t >= o) ? sc[t-o] : 0;
    __syncthreads();
    sc[t] += add;
    __syncthreads();
  }
  if(t == 0) offs[0] = 0;
  offs[t+1] = sc[t];
}
__global__ void k_csr_fill(const int* __restrict__ ei, const int* __restrict__ offs,
                           int* pos, int* csr_src){
  int e = blockIdx.x*256 + threadIdx.x;
  if(e < NEDGE + NIMG){
    int s, d;
    if(e < NEDGE){ s = ei[e]; d = ei[NEDGE+e]; }
    else { s = e - NEDGE; d = s; }
    int slot = offs[d] + atomicAdd(&pos[d], 1);
    csr_src[slot] = s;
  }
}

// ---------------- encode: 1x1 conv + BN + relu + conf, write padded NHWC ----
__launch_bounds__(256, 2)
__global__ void k_encode(const float* __restrict__ x, const float* __restrict__ conf,
                         const unsigned short* __restrict__ Wfe,
                         const float* __restrict__ fe_b, const float* __restrict__ fe_g,
                         const float* __restrict__ fe_beta,
                         unsigned short* __restrict__ xe_pad){
  __shared__ char lds[49152];          // xa 32KB (f32 swizzled) + wb 16KB
  char* xa = lds; char* wb = lds + 32768;
  int tid = threadIdx.x;
  int n = blockIdx.x >> 3, rg = blockIdx.x & 7;
  int hw0 = rg*128;
  {
    int q = tid >> 3, c0 = tid & 7;
    const float* xb = x + (size_t)n*CINCH*HWPIX + hw0;
    #pragma unroll
    for(int cc = 0; cc < 8; ++cc){
      int c = cc*8 + c0;
      float4 v = *(const float4*)(xb + (size_t)c*HWPIX + q*4);
      float vv[4] = {v.x, v.y, v.z, v.w};
      #pragma unroll
      for(int i = 0; i < 4; ++i){
        int p = q*4 + i;
        *(float*)(xa + p*256 + ((cc ^ (p&7))*32) + c0*4) = vv[i];
      }
    }
    #pragma unroll
    for(int it = 0; it < 4; ++it){
      uint4 w = *(const uint4*)((const char*)Wfe + it*4096 + tid*16);
      *(uint4*)(wb + it*4096 + tid*16) = w;
    }
  }
  __syncthreads();
  int wid = tid>>6, lane = tid&63;
  int wr = wid>>1, wc = wid&1, fr = lane&15, fq = lane>>4;
  f32x4 acc[4][4];
  #pragma unroll
  for(int a = 0; a < 4; ++a)
    #pragma unroll
    for(int b = 0; b < 4; ++b) acc[a][b] = (f32x4){0.f,0.f,0.f,0.f};
  #pragma unroll
  for(int kc = 0; kc < 2; ++kc){
    bf16x8 af[4], bfr[4];
    #pragma unroll
    for(int mi = 0; mi < 4; ++mi){
      int p = wr*64 + mi*16 + fr;
      int u = kc*4 + fq;
      const float* src = (const float*)(xa + p*256 + ((u ^ (p&7))*32));
      float4 lo = *(const float4*)src;
      float4 hi = *(const float4*)(src+4);
      bf16x8 a;
      a[0]=(short)f2bf(lo.x); a[1]=(short)f2bf(lo.y); a[2]=(short)f2bf(lo.z); a[3]=(short)f2bf(lo.w);
      a[4]=(short)f2bf(hi.x); a[5]=(short)f2bf(hi.y); a[6]=(short)f2bf(hi.z); a[7]=(short)f2bf(hi.w);
      af[mi] = a;
    }
    #pragma unroll
    for(int nf = 0; nf < 4; ++nf){
      int co = wc*64 + nf*16 + fr;
      int slot = (kc*4 + fq) ^ (co&7);
      bfr[nf] = *(const bf16x8*)(wb + co*128 + slot*16);
    }
    #pragma unroll
    for(int mi = 0; mi < 4; ++mi)
      #pragma unroll
      for(int nf = 0; nf < 4; ++nf)
        acc[mi][nf] = __builtin_amdgcn_mfma_f32_16x16x32_bf16(af[mi], bfr[nf], acc[mi][nf], 0,0,0);
  }
  __syncthreads();
  {
    const float rs = 0.9999950000374997f;
    float kb[4], ks[4], kbe[4];
    #pragma unroll
    for(int nf = 0; nf < 4; ++nf){
      int co = wc*64 + nf*16 + fr;
      kb[nf] = fe_b[co]; ks[nf] = fe_g[co]*rs; kbe[nf] = fe_beta[co];
    }
    #pragma unroll
    for(int mi = 0; mi < 4; ++mi)
      #pragma unroll
      for(int j = 0; j < 4; ++j){
        int px = wr*64 + mi*16 + fq*4 + j;
        float cf = conf[(size_t)n*HWPIX + hw0 + px];
        #pragma unroll
        for(int nf = 0; nf < 4; ++nf){
          float v = (acc[mi][nf][j] + kb[nf])*ks[nf] + kbe[nf];
          v = fmaxf(v, 0.f)*cf;
          int co = wc*64 + nf*16 + fr;
          *(unsigned short*)(xa + px*256 + ((co*2) ^ (((px>>2)&7)<<4))) = f2bf(v);
        }
      }
  }
  __syncthreads();
  {
    int p = tid>>1, half = tid&1;
    int r = rg*4 + (p>>5), c = p&31;
    unsigned short* dst = xe_pad + ((size_t)n*PPIX + (r+1)*PW2 + (c+1))*128 + half*64;
    #pragma unroll
    for(int s = 0; s < 8; ++s){
      int slot = half*8 + s;
      uint4 v = *(uint4*)(xa + p*256 + ((slot*16) ^ (((p>>2)&7)<<4)));
      *(uint4*)(dst + s*8) = v;
    }
  }
}

// ---------------- 3x3 conv: 512 threads / 8 waves, 8 rows x 128 co per block
// LDS: [0, 92480)      A tile: 340 pixels (10 padded rows x 34 cols) x 272B
//      [92480, +64KB)  W double buffer (2 x 32KB), reused as epilogue scratch
__launch_bounds__(512, 2)
__global__ void k_conv3(const unsigned short* __restrict__ inp,   // padded NHWC bf16
                        const unsigned short* __restrict__ Wb,    // [9][128][16slots][8] pre-swizzled
                        const float* __restrict__ bnb, const float* __restrict__ bng,
                        const float* __restrict__ bnbe,
                        unsigned short* __restrict__ outp,
                        float* __restrict__ xnode_acc, int mode){  // 0: padded out, 1: flat out + xnode
  extern __shared__ char lds[];
  char* Ab = lds;
  char* Wd = lds + 92480;
  int tid = threadIdx.x;
  int n = blockIdx.x>>2, rg = blockIdx.x&3;   // rg: 8-row group (0..3)

  // ---- stage A tile (5440 granules of 16B) + W tap0 (4 rounds of 8KB) ----
  const char* asrc = (const char*)(inp + ((size_t)n*PPIX + (size_t)rg*8*PW2)*128);
  const char* wsrc = (const char*)Wb;
  uint4 av[11];
  #pragma unroll
  for(int it = 0; it < 11; ++it){
    int i = tid + it*512;
    if(it < 10 || i < 5440) av[it] = *(const uint4*)(asrc + (size_t)i*16);
  }
  uint4 st[4];
  #pragma unroll
  for(int it = 0; it < 4; ++it) st[it] = *(const uint4*)(wsrc + it*8192 + tid*16);
  #pragma unroll
  for(int it = 0; it < 11; ++it){
    int i = tid + it*512;
    if(it < 10 || i < 5440) *(uint4*)(Ab + (i>>4)*272 + (i&15)*16) = av[it];
  }
  #pragma unroll
  for(int it = 0; it < 4; ++it) *(uint4*)(Wd + it*8192 + tid*16) = st[it];
  __syncthreads();

  int wid = tid>>6, lane = tid&63;
  int wr = wid>>1, wc = wid&1, fr = lane&15, fq = lane>>4;   // wr 0..3, wc 0..1
  int pixb[4];
  #pragma unroll
  for(int mi = 0; mi < 4; ++mi){
    int p = wr*64 + mi*16 + fr;                 // block-local pixel 0..255
    pixb[mi] = ((p>>5)+1)*PW2 + (p&31) + 1;     // tile-local padded pixel
  }
  f32x4 acc[4][4];
  #pragma unroll
  for(int a = 0; a < 4; ++a)
    #pragma unroll
    for(int b = 0; b < 4; ++b) acc[a][b] = (f32x4){0.f,0.f,0.f,0.f};

  for(int tap = 0; tap < 9; ++tap){
    char* cur = Wd + (tap&1)*32768;
    int dy = tap/3 - 1, dx = tap - (tap/3)*3 - 1;
    int pd = dy*PW2 + dx;
    if(tap < 8){
      #pragma unroll
      for(int it = 0; it < 4; ++it)
        st[it] = *(const uint4*)(wsrc + (size_t)(tap+1)*32768 + it*8192 + tid*16);
    }
    #pragma unroll
    for(int kc = 0; kc < 4; ++kc){
      bf16x8 af[4], bfr[4];
      #pragma unroll
      for(int mi = 0; mi < 4; ++mi)
        af[mi] = *(const bf16x8*)(Ab + (pixb[mi]+pd)*272 + kc*64 + fq*16);
      #pragma unroll
      for(int nf = 0; nf < 4; ++nf){
        int co = wc*64 + nf*16 + fr;
        int slot = (kc*4 + fq) ^ (co&7);
        bfr[nf] = *(const bf16x8*)(cur + co*256 + slot*16);
      }
      #pragma unroll
      for(int mi = 0; mi < 4; ++mi)
        #pragma unroll
        for(int nf = 0; nf < 4; ++nf)
          acc[mi][nf] = __builtin_amdgcn_mfma_f32_16x16x32_bf16(af[mi], bfr[nf], acc[mi][nf], 0,0,0);
    }
    if(tap < 8){
      char* nxt = Wd + ((tap+1)&1)*32768;
      #pragma unroll
      for(int it = 0; it < 4; ++it) *(uint4*)(nxt + it*8192 + tid*16) = st[it];
    }
    __syncthreads();
  }
  // epilogue: BN + relu -> LDS transpose (in W region, 64KB) -> coalesced store
  char* eb = Wd;
  {
    const float rs = 0.9999950000374997f;
    float kb[4], ks[4], kbe[4];
    #pragma unroll
    for(int nf = 0; nf < 4; ++nf){
      int co = wc*64 + nf*16 + fr;
      kb[nf] = bnb[co]; ks[nf] = bng[co]*rs; kbe[nf] = bnbe[co];
    }
    #pragma unroll
    for(int mi = 0; mi < 4; ++mi)
      #pragma unroll
      for(int j = 0; j < 4; ++j){
        int px = wr*64 + mi*16 + fq*4 + j;      // 0..255
        #pragma unroll
        for(int nf = 0; nf < 4; ++nf){
          float v = (acc[mi][nf][j] + kb[nf])*ks[nf] + kbe[nf];
          v = fmaxf(v, 0.f);
          int co = wc*64 + nf*16 + fr;
          *(unsigned short*)(eb + px*256 + ((co*2) ^ (((px>>2)&7)<<4))) = f2bf(v);
        }
      }
  }
  __syncthreads();
  {
    int p = tid>>1, half = tid&1;               // p 0..255
    int r = rg*8 + (p>>5), c = p&31;
    unsigned short* dst;
    if(mode == 0) dst = outp + ((size_t)n*PPIX + (r+1)*PW2 + (c+1))*128 + half*64;
    else          dst = outp + ((size_t)n*HWPIX + rg*256 + p)*128 + half*64;
    #pragma unroll
    for(int s = 0; s < 8; ++s){
      int slot = half*8 + s;
      uint4 v = *(uint4*)(eb + p*256 + ((slot*16) ^ (((p>>2)&7)<<4)));
      *(uint4*)(dst + s*8) = v;
    }
  }
  if(mode == 1){
    int co = tid & 127, g = tid>>7;             // g 0..3, 64 px each
    float sum = 0.f;
    #pragma unroll 8
    for(int i = 0; i < 64; ++i){
      int px = g*64 + i;
      sum += bf2f(*(unsigned short*)(eb + px*256 + ((co*2) ^ (((px>>2)&7)<<4))));
    }
    atomicAdd(&xnode_acc[n*HIDC + co], sum);
  }
}

// ---------------- GAT linear: h = x@lin, plus per-head attn dots ------------
__global__ void k_gat_lin(const float* __restrict__ xin, float scale,
                          const float* __restrict__ lin,
                          const float* __restrict__ as_, const float* __restrict__ ad_,
                          float* __restrict__ h, float* __restrict__ a_s, float* __restrict__ a_d){
  __shared__ float xs[128];
  __shared__ float rs0[4], rs1[4], rd0[4], rd1[4];
  int n = blockIdx.x, t = threadIdx.x;
  if(t < 128) xs[t] = xin[n*128 + t]*scale;
  __syncthreads();
  float o0 = 0.f, o1 = 0.f;
  for(int k = 0; k < 128; ++k){
    float xv = xs[k];
    o0 += xv*lin[k*512 + t];
    o1 += xv*lin[k*512 + t + 256];
  }
  h[(size_t)n*512 + t] = o0;
  h[(size_t)n*512 + t + 256] = o1;
  float s0 = o0*as_[t], s1 = o1*as_[t+256];
  float d0 = o0*ad_[t], d1 = o1*ad_[t+256];
  #pragma unroll
  for(int o = 32; o; o >>= 1){
    s0 += __shfl_down(s0, o); s1 += __shfl_down(s1, o);
    d0 += __shfl_down(d0, o); d1 += __shfl_down(d1, o);
  }
  int w = t>>6;
  if((t&63) == 0){ rs0[w]=s0; rs1[w]=s1; rd0[w]=d0; rd1[w]=d1; }
  __syncthreads();
  if(t < 4){
    if(t < 2){
      a_s[n*4+t] = rs0[2*t] + rs0[2*t+1];
      a_d[n*4+t] = rd0[2*t] + rd0[2*t+1];
    } else {
      a_s[n*4+t] = rs1[2*(t-2)] + rs1[2*(t-2)+1];
      a_d[n*4+t] = rd1[2*(t-2)] + rd1[2*(t-2)+1];
    }
  }
}

// ---------------- GAT aggregate: per-dst softmax + weighted sum -------------
__global__ void k_gat_aggr(const int* __restrict__ offs, const int* __restrict__ csr_src,
                           const float* __restrict__ a_s, const float* __restrict__ a_d,
                           const float* __restrict__ h, const float* __restrict__ bias,
                           float* __restrict__ y){
  __shared__ int ssrc[2048];
  __shared__ float sex[4][2048];
  __shared__ float out4[512];
  __shared__ float adn[4], smax[4], sden[4];
  __shared__ float wred[4][4];
  int n = blockIdx.x, t = threadIdx.x;
  int base = offs[n], deg = offs[n+1] - base;
  if(t < 4) adn[t] = a_d[n*4 + t];
  __syncthreads();
  bool cached = (deg <= 2048);
  float lm0=-1e30f, lm1=-1e30f, lm2=-1e30f, lm3=-1e30f;
  for(int e = t; e < deg; e += 256){
    int s = csr_src[base + e];
    float v0 = a_s[s*4+0] + adn[0]; v0 = v0 > 0.f ? v0 : 0.2f*v0;
    float v1 = a_s[s*4+1] + adn[1]; v1 = v1 > 0.f ? v1 : 0.2f*v1;
    float v2 = a_s[s*4+2] + adn[2]; v2 = v2 > 0.f ? v2 : 0.2f*v2;
    float v3 = a_s[s*4+3] + adn[3]; v3 = v3 > 0.f ? v3 : 0.2f*v3;
    if(cached){ ssrc[e]=s; sex[0][e]=v0; sex[1][e]=v1; sex[2][e]=v2; sex[3][e]=v3; }
    lm0 = fmaxf(lm0, v0); lm1 = fmaxf(lm1, v1); lm2 = fmaxf(lm2, v2); lm3 = fmaxf(lm3, v3);
  }
  #pragma unroll
  for(int o = 32; o; o >>= 1){
    lm0 = fmaxf(lm0, __shfl_down(lm0, o)); lm1 = fmaxf(lm1, __shfl_down(lm1, o));
    lm2 = fmaxf(lm2, __shfl_down(lm2, o)); lm3 = fmaxf(lm3, __shfl_down(lm3, o));
  }
  int w = t>>6;
  if((t&63) == 0){ wred[w][0]=lm0; wred[w][1]=lm1; wred[w][2]=lm2; wred[w][3]=lm3; }
  __syncthreads();
  if(t < 4) smax[t] = fmaxf(fmaxf(wred[0][t], wred[1][t]), fmaxf(wred[2][t], wred[3][t]));
  __syncthreads();
  float m0 = smax[0], m1 = smax[1], m2 = smax[2], m3 = smax[3];
  float ls0=0.f, ls1=0.f, ls2=0.f, ls3=0.f;
  for(int e = t; e < deg; e += 256){
    float e0, e1, e2, e3;
    if(cached){ e0 = sex[0][e]; e1 = sex[1][e]; e2 = sex[2][e]; e3 = sex[3][e]; }
    else {
      int s = csr_src[base + e];
      e0 = a_s[s*4+0] + adn[0]; e0 = e0 > 0.f ? e0 : 0.2f*e0;
      e1 = a_s[s*4+1] + adn[1]; e1 = e1 > 0.f ? e1 : 0.2f*e1;
      e2 = a_s[s*4+2] + adn[2]; e2 = e2 > 0.f ? e2 : 0.2f*e2;
      e3 = a_s[s*4+3] + adn[3]; e3 = e3 > 0.f ? e3 : 0.2f*e3;
    }
    e0 = __expf(e0-m0); e1 = __expf(e1-m1); e2 = __expf(e2-m2); e3 = __expf(e3-m3);
    if(cached){ sex[0][e]=e0; sex[1][e]=e1; sex[2][e]=e2; sex[3][e]=e3; }
    ls0 += e0; ls1 += e1; ls2 += e2; ls3 += e3;
  }
  #pragma unroll
  for(int o = 32; o; o >>= 1){
    ls0 += __shfl_down(ls0, o); ls1 += __shfl_down(ls1, o);
    ls2 += __shfl_down(ls2, o); ls3 += __shfl_down(ls3, o);
  }
  __syncthreads();   // wred(max) fully consumed
  if((t&63) == 0){ wred[w][0]=ls0; wred[w][1]=ls1; wred[w][2]=ls2; wred[w][3]=ls3; }
  __syncthreads();
  if(t < 4) sden[t] = wred[0][t] + wred[1][t] + wred[2][t] + wred[3][t] + 1e-16f;
  __syncthreads();
  #pragma unroll
  for(int oo = 0; oo < 2; ++oo){
    int o = t + oo*256;
    int hd = o>>7, d = o&127;
    float mh = smax[hd];
    float accv = 0.f;
    for(int e = 0; e < deg; ++e){
      float ex; int s;
      if(cached){ ex = sex[hd][e]; s = ssrc[e]; }
      else {
        s = csr_src[base + e];
        float v = a_s[s*4+hd] + adn[hd]; v = v > 0.f ? v : 0.2f*v;
        ex = __expf(v - mh);
      }
      accv += ex * h[(size_t)s*512 + hd*128 + d];
    }
    out4[o] = accv / sden[hd];
  }
  __syncthreads();
  if(t < 128){
    float v = (out4[t] + out4[128+t] + out4[256+t] + out4[384+t])*0.25f + bias[t];
    y[n*128 + t] = fmaxf(v, 0.f);
  }
}

// ---------------- per-node bias for final conv: nb = op_w @ xg2 + op_b ------
__global__ void k_nodebias(const float* __restrict__ xg2, const float* __restrict__ op_w,
                           const float* __restrict__ op_b, float* __restrict__ nb){
  int g = blockIdx.x*256 + threadIdx.x;
  if(g < NIMG*64){
    int n = g>>6, co = g&63;
    float acc = op_b[co];
    for(int k = 0; k < 128; ++k) acc += op_w[co*128+k]*xg2[n*128+k];
    nb[g] = acc;
  }
}

// ---------------- final 1x1 conv: out = op_w@xp2 + nb, NCHW f32 -------------
__launch_bounds__(256, 2)
__global__ void k_outconv(const unsigned short* __restrict__ xp2,
                          const unsigned short* __restrict__ Wop,
                          const float* __restrict__ nb, float* __restrict__ out){
  __shared__ char lds[16384];
  int tid = threadIdx.x;
  int n = blockIdx.x>>3, rg = blockIdx.x&7;
  #pragma unroll
  for(int it = 0; it < 4; ++it){
    uint4 v = *(const uint4*)((const char*)Wop + it*4096 + tid*16);
    *(uint4*)(lds + it*4096 + tid*16) = v;
  }
  __syncthreads();
  int wid = tid>>6, lane = tid&63;
  int wr = wid>>1, wc = wid&1, fr = lane&15, fq = lane>>4;
  f32x4 acc[4][2];
  #pragma unroll
  for(int a = 0; a < 4; ++a){ acc[a][0] = (f32x4){0.f,0.f,0.f,0.f}; acc[a][1] = (f32x4){0.f,0.f,0.f,0.f}; }
  const unsigned short* abase = xp2 + ((size_t)n*HWPIX + rg*128)*128;
  #pragma unroll
  for(int kc = 0; kc < 4; ++kc){
    bf16x8 af[4], bfr[2];
    #pragma unroll
    for(int mi = 0; mi < 4; ++mi){
      int p = wr*64 + mi*16 + fr;
      af[mi] = *(const bf16x8*)(abase + p*128 + kc*32 + fq*8);
    }
    #pragma unroll
    for(int nf = 0; nf < 2; ++nf){
      int co = wc*32 + nf*16 + fr;
      int slot = (kc*4 + fq) ^ (co&7);
      bfr[nf] = *(const bf16x8*)(lds + co*256 + slot*16);
    }
    #pragma unroll
    for(int mi = 0; mi < 4; ++mi)
      #pragma unroll
      for(int nf = 0; nf < 2; ++nf)
        acc[mi][nf] = __builtin_amdgcn_mfma_f32_16x16x32_bf16(af[mi], bfr[nf], acc[mi][nf], 0,0,0);
  }
  #pragma unroll
  for(int mi = 0; mi < 4; ++mi)
    #pragma unroll
    for(int nf = 0; nf < 2; ++nf){
      int co = wc*32 + nf*16 + fr;
      int hw = rg*128 + wr*64 + mi*16 + fq*4;
      float nbv = nb[n*64 + co];
      float4 v = { acc[mi][nf][0]+nbv, acc[mi][nf][1]+nbv, acc[mi][nf][2]+nbv, acc[mi][nf][3]+nbv };
      *(float4*)(out + ((size_t)n*64 + co)*HWPIX + hw) = v;
    }
}

// ---------------- host launch ----------------------------------------------
extern "C" void kernel_launch(void* const* d_in, const int* in_sizes, int n_in,
                              void* d_out, int out_size, void* d_ws, size_t ws_size,
                              hipStream_t stream){
  const float* x       = (const float*)d_in[0];
  const int*   ei      = (const int*)d_in[1];
  const float* conf    = (const float*)d_in[2];
  const float* fe_w    = (const float*)d_in[3];
  const float* fe_b    = (const float*)d_in[4];
  const float* fe_g    = (const float*)d_in[5];
  const float* fe_beta = (const float*)d_in[6];
  const float* sp_w1   = (const float*)d_in[7];
  const float* sp_b1   = (const float*)d_in[8];
  const float* sp_g1   = (const float*)d_in[9];
  const float* sp_be1  = (const float*)d_in[10];
  const float* sp_w2   = (const float*)d_in[11];
  const float* sp_b2   = (const float*)d_in[12];
  const float* sp_g2   = (const float*)d_in[13];
  const float* sp_be2  = (const float*)d_in[14];
  const float* g1_lin  = (const float*)d_in[15];
  const float* g1_as   = (const float*)d_in[16];
  const float* g1_ad   = (const float*)d_in[17];
  const float* g1_b    = (const float*)d_in[18];
  const float* g2_lin  = (const float*)d_in[19];
  const float* g2_as   = (const float*)d_in[20];
  const float* g2_ad   = (const float*)d_in[21];
  const float* g2_b    = (const float*)d_in[22];
  const float* op_w    = (const float*)d_in[23];
  const float* op_b    = (const float*)d_in[24];
  float* out = (float*)d_out;

  char* ws = (char*)d_ws;
  size_t off = 0;
  auto alloc = [&](size_t bytes)->char*{
    char* p = ws + off; off += (bytes + 255) & ~(size_t)255; return p;
  };
  unsigned short* bigA  = (unsigned short*)alloc((size_t)NIMG*PPIX*128*2); // xe_pad, later xp2
  unsigned short* xp1   = (unsigned short*)alloc((size_t)NIMG*PPIX*128*2);
  unsigned short* Wb1   = (unsigned short*)alloc(147456*2);
  unsigned short* Wb2   = (unsigned short*)alloc(147456*2);
  unsigned short* Wfe   = (unsigned short*)alloc(8192*2);
  unsigned short* Wop   = (unsigned short*)alloc(8192*2);
  float* xnode_acc = (float*)alloc(NIMG*HIDC*4);
  float* h     = (float*)alloc((size_t)NIMG*512*4);
  float* a_s   = (float*)alloc(NIMG*4*4);
  float* a_d   = (float*)alloc(NIMG*4*4);
  float* xg1   = (float*)alloc(NIMG*HIDC*4);
  float* xg2   = (float*)alloc(NIMG*HIDC*4);
  int* cnt     = (int*)alloc(NIMG*4);
  int* pos     = (int*)alloc(NIMG*4);
  int* offs    = (int*)alloc((NIMG+1)*4);
  int* csr_src = (int*)alloc((NEDGE+NIMG)*4);
  float* nb    = (float*)alloc(NIMG*64*4);
  if(off > ws_size) return;   // workspace too small — bail cleanly
  unsigned short* xp2 = bigA; // reuse region A after conv1 consumed xe

  // 158016 B dynamic LDS for k_conv3 (A tile 92480 + W dbuf 65536); 1 block/CU,
  // 8 waves = 2 waves/SIMD.
  hipFuncSetAttribute((const void*)k_conv3,
                      hipFuncAttributeMaxDynamicSharedMemorySize, 158016);

  k_init<<<1024, 256, 0, stream>>>(bigA, xp1, xnode_acc, cnt, pos);
  k_wconv<<<576, 256, 0, stream>>>(sp_w1, sp_w2, fe_w, op_w, Wb1, Wb2, Wfe, Wop);
  k_csr_count<<<(NEDGE+255)/256, 256, 0, stream>>>(ei, cnt);
  k_csr_scan<<<1, 512, 0, stream>>>(cnt, offs);
  k_csr_fill<<<(NEDGE+NIMG+255)/256, 256, 0, stream>>>(ei, offs, pos, csr_src);
  k_encode<<<4096, 256, 0, stream>>>(x, conf, Wfe, fe_b, fe_g, fe_beta, bigA);
  k_conv3<<<2048, 512, 158016, stream>>>(bigA, Wb1, sp_b1, sp_g1, sp_be1, xp1, xnode_acc, 0);
  k_conv3<<<2048, 512, 158016, stream>>>(xp1, Wb2, sp_b2, sp_g2, sp_be2, xp2, xnode_acc, 1);
  k_gat_lin<<<512, 256, 0, stream>>>(xnode_acc, 1.f/1024.f, g1_lin, g1_as, g1_ad, h, a_s, a_d);
  k_gat_aggr<<<512, 256, 0, stream>>>(offs, csr_src, a_s, a_d, h, g1_b, xg1);
  k_gat_lin<<<512, 256, 0, stream>>>(xg1, 1.f, g2_lin, g2_as, g2_ad, h, a_s, a_d);
  k_gat_aggr<<<512, 256, 0, stream>>>(offs, csr_src, a_s, a_d, h, g2_b, xg2);
  k_nodebias<<<(NIMG*64+255)/256, 256, 0, stream>>>(xg2, op_w, op_b, nb);
  k_outconv<<<4096, 256, 0, stream>>>(xp2, Wop, nb, out);
}